// Round 2
// baseline (140.456 us; speedup 1.0000x reference)
//
#include <hip/hip_runtime.h>

#define BSZ 8
#define NQ 2048
#define MP 64
#define DD 1024
#define K2ALL 2048   // packed interleaved ushort per (b,m) row: [m2, -2*m2*p]
#define BN 16        // query rows per block
#define BK 64        // d per chunk
#define K2 128       // 2*BK interleaved bf16 per chunk
#define LDK 136      // K2 + 8 ushort pad
#define KT 16        // DD / BK
#define NTILES (NQ / BN)   // 128

typedef __bf16 bf16x8 __attribute__((ext_vector_type(8)));
typedef float f32x4 __attribute__((ext_vector_type(4)));
typedef unsigned short us8 __attribute__((ext_vector_type(8)));

__device__ __forceinline__ unsigned short f2bf(float f) {
    union { float f; unsigned int u; } v; v.f = f;
    unsigned int u = v.u;
    return (unsigned short)((u + 0x7FFFu + ((u >> 16) & 1u)) >> 16);  // RNE
}

// Pass 1: pack proto/mask -> bf16 [m2, -2*m2*p] interleaved + fp32 pterm.
// grid = 512 blocks (one per (b,m) row), 256 threads (one float4 of d each).
__global__ __launch_bounds__(256) void pack_kernel(
    const float* __restrict__ proto,
    const float* __restrict__ mask,
    unsigned short* __restrict__ Pp,
    float* __restrict__ Pterm)
{
    const int row = blockIdx.x;          // = b*64 + m (proto/mask are [b][m][d] flat)
    const int t = threadIdx.x;

    const float4 mk = *(const float4*)(mask  + (size_t)row * DD + 4 * t);
    const float4 pr = *(const float4*)(proto + (size_t)row * DD + 4 * t);

    const float m2x = mk.x * mk.x, m2y = mk.y * mk.y,
                m2z = mk.z * mk.z, m2w = mk.w * mk.w;
    const float ax = mk.x * pr.x, ay = mk.y * pr.y,
                az = mk.z * pr.z, aw = mk.w * pr.w;
    float pacc = ax * ax + ay * ay + az * az + aw * aw;

    us8 o;
    o[0] = f2bf(m2x); o[1] = f2bf(-2.f * m2x * pr.x);
    o[2] = f2bf(m2y); o[3] = f2bf(-2.f * m2y * pr.y);
    o[4] = f2bf(m2z); o[5] = f2bf(-2.f * m2z * pr.z);
    o[6] = f2bf(m2w); o[7] = f2bf(-2.f * m2w * pr.w);
    *(us8*)(Pp + (size_t)row * K2ALL + 8 * t) = o;

    // block-reduce pacc (exact fp32 pterm)
    __shared__ float red[4];
    #pragma unroll
    for (int off = 32; off > 0; off >>= 1)
        pacc += __shfl_down(pacc, off, 64);
    const int lane = t & 63, w = t >> 6;
    if (lane == 0) red[w] = pacc;
    __syncthreads();
    if (t == 0) Pterm[row] = red[0] + red[1] + red[2] + red[3];
}

// Pass 2: logits GEMM. 1024 blocks (b = bid&7 -> XCD-affine), 256 threads.
// Each wave owns one 16-wide m slice; B frags direct global->reg (L2),
// query staged through double-buffered LDS, 1 barrier per chunk.
__global__ __launch_bounds__(256, 4) void proto_main_kernel(
    const float* __restrict__ query,
    const unsigned short* __restrict__ Pp,
    const float* __restrict__ Pterm,
    const float* __restrict__ scale,
    float* __restrict__ out)
{
    __shared__ unsigned short Qs[2][BN][LDK];

    const int tid = threadIdx.x;
    const int bid = blockIdx.x;
    const int b  = bid & 7;
    const int n0 = (bid >> 3) * BN;

    // query staging map: one float4 per thread per chunk
    const int qrow = tid >> 4;           // 0..15
    const int qc   = tid & 15;           // float4 col within 64-d chunk
    const float* qptr = query + ((size_t)b * NQ + n0 + qrow) * DD + 4 * qc;

    const int lane = tid & 63;
    const int wid  = tid >> 6;           // m-slice owner
    const int lrow = lane & 15;
    const int lq   = (lane >> 4) * 8;

    const int mcol = 16 * wid + lrow;    // this lane's B row / output m
    const unsigned short* bptr = Pp + ((size_t)(b * MP + mcol)) * K2ALL + lq;

    f32x4 acc = (f32x4){0.f, 0.f, 0.f, 0.f};
    float4 q[2];
    bf16x8 bv[2][4];

    // hoisted epilogue scalars (L2 hits, latency hidden behind the loop)
    const float pt = Pterm[b * MP + mcol];
    const float sc = scale[0] * (1.0f / (float)DD);

    // prime: query chunks 0,1 ; B chunk 0
    q[0] = *(const float4*)(qptr);
    q[1] = *(const float4*)(qptr + BK);
    #pragma unroll
    for (int i = 0; i < 4; ++i)
        bv[0][i] = *(const bf16x8*)(bptr + 32 * i);

    #pragma unroll
    for (int kt = 0; kt < KT; ++kt) {
        const int cur = kt & 1;

        // convert + stage chunk kt (q loaded 2 iterations ago -> vmcnt drained)
        {
            const float4 qq = q[cur];
            us8 o;
            o[0] = f2bf(qq.x * qq.x); o[1] = f2bf(qq.x);
            o[2] = f2bf(qq.y * qq.y); o[3] = f2bf(qq.y);
            o[4] = f2bf(qq.z * qq.z); o[5] = f2bf(qq.z);
            o[6] = f2bf(qq.w * qq.w); o[7] = f2bf(qq.w);
            *(us8*)(&Qs[cur][qrow][8 * qc]) = o;
        }
        __syncthreads();   // buf[cur] ready; dbuf => safe with one barrier/chunk

        // prefetch AFTER the barrier so its vmcnt isn't drained by it
        if (kt + 2 < KT)
            q[cur] = *(const float4*)(qptr + (kt + 2) * BK);
        if (kt + 1 < KT) {
            #pragma unroll
            for (int i = 0; i < 4; ++i)
                bv[(kt + 1) & 1][i] =
                    *(const bf16x8*)(bptr + (kt + 1) * K2 + 32 * i);
        }

        // MFMA over chunk kt: A from LDS, B from regs (loaded last iter)
        #pragma unroll
        for (int i = 0; i < 4; ++i) {
            const bf16x8 a = *(const bf16x8*)(&Qs[cur][lrow][32 * i + lq]);
            acc = __builtin_amdgcn_mfma_f32_16x16x32_bf16(a, bv[cur][i], acc, 0, 0, 0);
        }
    }

    // epilogue: n = n0 + (lane>>4)*4 + r, m = mcol
    const size_t ob = ((size_t)b * NQ + (size_t)(n0 + (lane >> 4) * 4)) * MP + mcol;
    #pragma unroll
    for (int r = 0; r < 4; ++r)
        out[ob + (size_t)r * MP] = (acc[r] + pt) * sc;
}

extern "C" void kernel_launch(void* const* d_in, const int* in_sizes, int n_in,
                              void* d_out, int out_size, void* d_ws, size_t ws_size,
                              hipStream_t stream) {
    (void)in_sizes; (void)n_in; (void)ws_size; (void)out_size;
    const float* proto = (const float*)d_in[0];
    const float* mask  = (const float*)d_in[1];
    const float* query = (const float*)d_in[2];
    const float* scale = (const float*)d_in[5];
    float* out = (float*)d_out;

    unsigned short* Pp = (unsigned short*)d_ws;                    // 2 MiB
    float* Pterm = (float*)((char*)d_ws + (size_t)BSZ * MP * K2ALL * 2);  // +2 KiB

    pack_kernel<<<dim3(BSZ * MP), dim3(256), 0, stream>>>(proto, mask, Pp, Pterm);
    proto_main_kernel<<<dim3(BSZ * NTILES), dim3(256), 0, stream>>>(
        query, Pp, Pterm, scale, out);
}